// Round 1
// baseline (393.929 us; speedup 1.0000x reference)
//
#include <hip/hip_runtime.h>
#include <math.h>

// Problem constants (from reference): x [B=8, C=1, D=3, H=1536, W=1536] fp32
#define Hh   1536
#define Ww   1536
#define Dd   3
#define Bb   8
#define TH   8           // output rows per block
#define TW   768         // output cols per block (2 tiles across W)
#define C4n  (TW / 4)    // 192 float4 per row
#define ROWP (TW + 8)    // padded LDS row: [0..2]=pad, [3]=left halo, [4..TW+3]=tile, [TW+4]=right halo, [TW+5..7]=pad
#define EPSf 1e-5f

__global__ __launch_bounds__(256) void nms3d_kernel(const float* __restrict__ x,
                                                    float* __restrict__ out) {
    __shared__ float sm[TH + 2][ROWP];   // depth-max m, rows h0-1 .. h0+TH

    const int tid = threadIdx.x;
    int blk = blockIdx.x;
    const int wt = blk & 1;              // 2 col-tiles
    blk >>= 1;
    const int s = blk % (Hh / TH);       // 192 row strips
    const int b = blk / (Hh / TH);

    const int h0 = s * TH;
    const int w0 = wt * TW;

    const size_t plane = (size_t)Hh * Ww;
    const float* xb = x + (size_t)b * Dd * plane;
    float*       ob = out + (size_t)b * Dd * plane;

    // ---------------- Phase 1: depth-max into LDS (vectorized) ----------------
    for (int task = tid; task < (TH + 2) * C4n; task += 256) {
        const int r = task / C4n;
        const int c = task - r * C4n;
        const int h = h0 - 1 + r;
        float4 mv;
        if (h < 0 || h >= Hh) {
            mv = make_float4(-INFINITY, -INFINITY, -INFINITY, -INFINITY);
        } else {
            const float* p = xb + (size_t)h * Ww + w0 + c * 4;
            const float4 a0 = *(const float4*)(p);
            const float4 a1 = *(const float4*)(p + plane);
            const float4 a2 = *(const float4*)(p + 2 * plane);
            mv.x = fmaxf(a0.x, fmaxf(a1.x, a2.x));
            mv.y = fmaxf(a0.y, fmaxf(a1.y, a2.y));
            mv.z = fmaxf(a0.z, fmaxf(a1.z, a2.z));
            mv.w = fmaxf(a0.w, fmaxf(a1.w, a2.w));
        }
        *(float4*)&sm[r][4 + c * 4] = mv;
    }
    // halo columns: padded col 3 = w0-1, padded col TW+4 = w0+TW
    if (tid < 2 * (TH + 2)) {
        const int side = tid / (TH + 2);
        const int r = tid - side * (TH + 2);
        const int h = h0 - 1 + r;
        const int w = side ? (w0 + TW) : (w0 - 1);
        float v = -INFINITY;
        if (h >= 0 && h < Hh && w >= 0 && w < Ww) {
            const float* p = xb + (size_t)h * Ww + w;
            v = fmaxf(p[0], fmaxf(p[plane], p[2 * plane]));
        }
        sm[r][side ? (TW + 4) : 3] = v;
    }
    __syncthreads();

    // ---------------- Phase 2: 3x3 spatial max + mask + store ----------------
    for (int task = tid; task < TH * C4n; task += 256) {
        const int r = task / C4n;
        const int c = task - r * C4n;
        const int lr = r + 1;

        // 6-wide window (padded cols 4c+3 .. 4c+8) maxed over 3 rows,
        // via three aligned ds_read_b128 per row.
        float m0 = -INFINITY, m1 = -INFINITY, m2 = -INFINITY;
        float m3 = -INFINITY, m4 = -INFINITY, m5 = -INFINITY;
#pragma unroll
        for (int rr = 0; rr < 3; rr++) {
            const float* row = &sm[lr - 1 + rr][0];
            const float4 q0 = *(const float4*)&row[c * 4];      // only .w used (col 4c+3)
            const float4 q1 = *(const float4*)&row[c * 4 + 4];  // cols 4c+4..4c+7
            const float4 q2 = *(const float4*)&row[c * 4 + 8];  // only .x used (col 4c+8)
            m0 = fmaxf(m0, q0.w);
            m1 = fmaxf(m1, q1.x);
            m2 = fmaxf(m2, q1.y);
            m3 = fmaxf(m3, q1.z);
            m4 = fmaxf(m4, q1.w);
            m5 = fmaxf(m5, q2.x);
        }
        const float p0 = fmaxf(m0, fmaxf(m1, m2));
        const float p1 = fmaxf(m1, fmaxf(m2, m3));
        const float p2 = fmaxf(m2, fmaxf(m3, m4));
        const float p3 = fmaxf(m3, fmaxf(m4, m5));

        const int h = h0 + r;
        const size_t base = (size_t)h * Ww + w0 + c * 4;
#pragma unroll
        for (int d = 0; d < Dd; d++) {
            const float4 xv = *(const float4*)(xb + base + (size_t)d * plane);
            float4 o;
            o.x = ((xv.x - p0) + EPSf > 0.0f) ? xv.x : 0.0f;
            o.y = ((xv.y - p1) + EPSf > 0.0f) ? xv.y : 0.0f;
            o.z = ((xv.z - p2) + EPSf > 0.0f) ? xv.z : 0.0f;
            o.w = ((xv.w - p3) + EPSf > 0.0f) ? xv.w : 0.0f;
            *(float4*)(ob + base + (size_t)d * plane) = o;
        }
    }
}

extern "C" void kernel_launch(void* const* d_in, const int* in_sizes, int n_in,
                              void* d_out, int out_size, void* d_ws, size_t ws_size,
                              hipStream_t stream) {
    const float* x = (const float*)d_in[0];
    float* out = (float*)d_out;
    const int grid = Bb * (Hh / TH) * (Ww / TW);  // 8 * 192 * 2 = 3072 blocks
    nms3d_kernel<<<dim3(grid), dim3(256), 0, stream>>>(x, out);
}

// Round 2
// 384.910 us; speedup vs baseline: 1.0234x; 1.0234x over previous
//
#include <hip/hip_runtime.h>
#include <math.h>

// x: [B=8, C=1, D=3, H=1536, W=1536] fp32
// out = (x - maxpool3x3x3(x) + 1e-5 > 0) ? x : 0, pool broadcast over depth.
// Separable: m[h][w] = max_d x[d][h][w]; mp = 3x3 spatial max of m.
// Register-rolling over h, wave-shuffle for horizontal halo. No LDS, no barriers.

#define Hh   1536
#define Ww   1536
#define EPSf 1e-5f
#define RPW  16                  // rows per wave
#define NBANDS (Ww / 256)        // 6 bands of 256 cols (64 lanes x float4)
#define NSTRIP (Hh / (4 * RPW))  // 24 strips of 64 rows (4 waves/block)

__global__ __launch_bounds__(256) void nms3d_kernel(const float* __restrict__ x,
                                                    float* __restrict__ out) {
    const int tid  = threadIdx.x;
    const int lane = tid & 63;
    const int wv   = tid >> 6;

    int blk = blockIdx.x;
    const int band = blk % NBANDS; blk /= NBANDS;
    const int s    = blk % NSTRIP;
    const int b    = blk / NSTRIP;

    const int w0 = band * 256;
    const int h0 = s * (4 * RPW) + wv * RPW;

    const size_t plane = (size_t)Hh * Ww;
    const float* xb = x + (size_t)b * 3 * plane;
    float*       ob = out + (size_t)b * 3 * plane;

    const int wc = w0 + lane * 4;
    // band-edge column: lane 0 covers w0-1, lane 63 covers w0+256
    const int  ecol = (lane == 0) ? (w0 - 1) : (w0 + 256);
    const bool eact = ((lane == 0) || (lane == 63)) && (ecol >= 0) && (ecol < Ww);

    const float NI = -INFINITY;

    // load one image row: x fragments (3 depths), depth-max m, edge depth-max e
    auto loadrow = [&](int h, float4& a0, float4& a1, float4& a2, float4& m, float& e) {
        if (h >= 0 && h < Hh) {            // wave-uniform branch
            const float* p = xb + (size_t)h * Ww + wc;
            a0 = *(const float4*)(p);
            a1 = *(const float4*)(p + plane);
            a2 = *(const float4*)(p + 2 * plane);
            m.x = fmaxf(a0.x, fmaxf(a1.x, a2.x));
            m.y = fmaxf(a0.y, fmaxf(a1.y, a2.y));
            m.z = fmaxf(a0.z, fmaxf(a1.z, a2.z));
            m.w = fmaxf(a0.w, fmaxf(a1.w, a2.w));
            e = NI;
            if (eact) {
                const float* q = xb + (size_t)h * Ww + ecol;
                e = fmaxf(q[0], fmaxf(q[plane], q[2 * plane]));
            }
        } else {
            m = make_float4(NI, NI, NI, NI);
            e = NI;
        }
    };

    float4 x0c, x1c, x2c, x0n, x1n, x2n;
    float4 m_p, m_c, m_n;
    float  e_p, e_c, e_n;

    {   // prologue: row h0-1 (m only) and row h0 (m + x)
        float4 d0, d1, d2;
        loadrow(h0 - 1, d0, d1, d2, m_p, e_p);
    }
    loadrow(h0, x0c, x1c, x2c, m_c, e_c);

#pragma unroll 4
    for (int i = 0; i < RPW; ++i) {
        const int h = h0 + i;
        loadrow(h + 1, x0n, x1n, x2n, m_n, e_n);

        // vertical max of the 3 depth-max rows
        float4 vm;
        vm.x = fmaxf(m_p.x, fmaxf(m_c.x, m_n.x));
        vm.y = fmaxf(m_p.y, fmaxf(m_c.y, m_n.y));
        vm.z = fmaxf(m_p.z, fmaxf(m_c.z, m_n.z));
        vm.w = fmaxf(m_p.w, fmaxf(m_c.w, m_n.w));

        // horizontal neighbors via shuffle; band edges from lanes 0/63 regs
        const float ev = fmaxf(e_p, fmaxf(e_c, e_n));
        const float fl = __shfl_up(vm.w, 1);
        const float fr = __shfl_down(vm.x, 1);
        const float left  = (lane == 0)  ? ev : fl;
        const float right = (lane == 63) ? ev : fr;

        float4 mp;
        mp.x = fmaxf(left, fmaxf(vm.x, vm.y));
        mp.y = fmaxf(vm.x, fmaxf(vm.y, vm.z));
        mp.z = fmaxf(vm.y, fmaxf(vm.z, vm.w));
        mp.w = fmaxf(vm.z, fmaxf(vm.w, right));

        float* po = ob + (size_t)h * Ww + wc;
        float4 o;
        o.x = ((x0c.x - mp.x) + EPSf > 0.0f) ? x0c.x : 0.0f;
        o.y = ((x0c.y - mp.y) + EPSf > 0.0f) ? x0c.y : 0.0f;
        o.z = ((x0c.z - mp.z) + EPSf > 0.0f) ? x0c.z : 0.0f;
        o.w = ((x0c.w - mp.w) + EPSf > 0.0f) ? x0c.w : 0.0f;
        *(float4*)(po) = o;
        o.x = ((x1c.x - mp.x) + EPSf > 0.0f) ? x1c.x : 0.0f;
        o.y = ((x1c.y - mp.y) + EPSf > 0.0f) ? x1c.y : 0.0f;
        o.z = ((x1c.z - mp.z) + EPSf > 0.0f) ? x1c.z : 0.0f;
        o.w = ((x1c.w - mp.w) + EPSf > 0.0f) ? x1c.w : 0.0f;
        *(float4*)(po + plane) = o;
        o.x = ((x2c.x - mp.x) + EPSf > 0.0f) ? x2c.x : 0.0f;
        o.y = ((x2c.y - mp.y) + EPSf > 0.0f) ? x2c.y : 0.0f;
        o.z = ((x2c.z - mp.z) + EPSf > 0.0f) ? x2c.z : 0.0f;
        o.w = ((x2c.w - mp.w) + EPSf > 0.0f) ? x2c.w : 0.0f;
        *(float4*)(po + 2 * plane) = o;

        // rotate rolling state
        m_p = m_c; m_c = m_n;
        e_p = e_c; e_c = e_n;
        x0c = x0n; x1c = x1n; x2c = x2n;
    }
}

extern "C" void kernel_launch(void* const* d_in, const int* in_sizes, int n_in,
                              void* d_out, int out_size, void* d_ws, size_t ws_size,
                              hipStream_t stream) {
    const float* x = (const float*)d_in[0];
    float* out = (float*)d_out;
    const int grid = 8 * NBANDS * NSTRIP;  // 8 * 6 * 24 = 1152 blocks
    nms3d_kernel<<<dim3(grid), dim3(256), 0, stream>>>(x, out);
}